// Round 1
// baseline (82.264 us; speedup 1.0000x reference)
//
#include <hip/hip_runtime.h>
#include <hip/hip_bf16.h>

#define H_ 256
#define W_ 256
#define C_ 128
#define NBPOS 1024   // N * 16 * 16 block positions
#define NACT 512

typedef __bf16 bf16x8 __attribute__((ext_vector_type(8)));
typedef float f32x4 __attribute__((ext_vector_type(4)));

// workspace layout (bytes)
#define SCALE_OFF 294912
#define SHIFT_OFF 295424
#define FLAGS_OFF 295936

// Repack weights HWIO fp32 -> bf16 tiles [tap][cin8][cout][8] (tile = tap*4+kc, 4096 bf16 each)
__global__ void prep_w_kernel(const float* __restrict__ w, __bf16* __restrict__ wprep) {
  int o = blockIdx.x * 256 + threadIdx.x;      // 576*256 = 147456 exact
  int j = o & 7;
  int cout = (o >> 3) & 127;
  int k8 = (o >> 10) & 15;
  int tap = o >> 14;
  int cin = k8 * 8 + j;
  wprep[o] = (__bf16)w[((size_t)tap * 128 + cin) * 128 + cout];
}

// BN fold + flag clear
__global__ void prep_misc_kernel(const float* __restrict__ b, const float* __restrict__ gamma,
                                 const float* __restrict__ beta, const float* __restrict__ mean,
                                 const float* __restrict__ var,
                                 float* __restrict__ scale, float* __restrict__ shift,
                                 int* __restrict__ flags) {
  int i = blockIdx.x * 256 + threadIdx.x;      // grid 4 -> 1024 threads
  if (i < 128) {
    float s = gamma[i] / sqrtf(var[i] + 1e-3f);
    scale[i] = s;
    shift[i] = (b[i] - mean[i]) * s + beta[i];
  }
  if (i < NBPOS) flags[i] = 0;
}

__global__ void flags_set_kernel(const int* __restrict__ active, int* __restrict__ flags) {
  int i = blockIdx.x * 256 + threadIdx.x;
  if (i < NACT) flags[active[i]] = 1;
}

// Copy non-active 16x16 blocks x -> y (active blocks written by conv kernel)
__global__ __launch_bounds__(256) void copy_kernel(const float* __restrict__ x,
                                                   const int* __restrict__ flags,
                                                   float* __restrict__ y) {
  int pb = blockIdx.x;
  if (flags[pb]) return;
  int bn = pb >> 8, by = (pb >> 4) & 15, bx = pb & 15;
  size_t base = (((size_t)bn * H_ + by * 16) * W_ + bx * 16) * C_;  // float index
  const float4* xs = (const float4*)x;
  float4* ys = (float4*)y;
  for (int i = threadIdx.x; i < 8192; i += 256) {   // 16 rows * 512 float4
    int row = i >> 9;
    int rem = i & 511;
    size_t idx4 = (base + (size_t)row * (W_ * C_)) / 4 + rem;
    ys[idx4] = xs[idx4];
  }
}

// One workgroup (4 waves, 256 thr) per active block.
// Implicit GEMM M=256 (16x16 spatial), N=128 (cout), K=1152 (9 taps * 128 cin).
// Patch staged bf16 in LDS in two 64-channel halves, XOR-swizzled.
__global__ __launch_bounds__(256, 2) void conv_kernel(
    const float* __restrict__ x, const __bf16* __restrict__ wprep,
    const float* __restrict__ scale, const float* __restrict__ shift,
    const int* __restrict__ active, float* __restrict__ y) {
  __shared__ unsigned char ldsA[324 * 128];   // 18*18 spatial x 64ch bf16 = 41472 B (swizzled)
  __shared__ unsigned char ldsB[8192];        // 32k x 128cout bf16 weight tile

  const int tid = threadIdx.x;
  const int lane = tid & 63;
  const int wid = tid >> 6;
  const int aid = active[blockIdx.x];
  const int bn = aid >> 8;
  const int by = (aid >> 4) & 15;
  const int bx = aid & 15;
  const int h0 = by * 16, w0 = bx * 16;
  const float* xb = x + (size_t)bn * (H_ * W_ * C_);

  // per-lane BN constants for epilogue (cout = nb*16 + (lane&15))
  float sc[8], sh[8];
  {
    int col = lane & 15;
#pragma unroll
    for (int nb = 0; nb < 8; ++nb) {
      sc[nb] = scale[nb * 16 + col];
      sh[nb] = shift[nb * 16 + col];
    }
  }

  f32x4 acc[4][8];
  f32x4 zero = {0.f, 0.f, 0.f, 0.f};
#pragma unroll
  for (int i = 0; i < 4; ++i)
#pragma unroll
    for (int j = 0; j < 8; ++j) acc[i][j] = zero;

  const uint4* wp4 = (const uint4*)wprep;
  // prefetch weight tile for u=0 (tap0, kc0)
  uint4 t0 = wp4[tid];
  uint4 t1 = wp4[256 + tid];

  const int koff = (lane >> 4) * 16;        // 16B k-chunk within 32 channels
  const int colb = (lane & 15) * 16;
  const int krow = (lane >> 4) * 2048;

  for (int half = 0; half < 2; ++half) {
    __syncthreads();  // all waves done reading ldsA from previous half
    // stage 18x18 x 64ch patch as bf16, swizzled: byte ^= (spatial&7)<<4
    for (int chunk = tid; chunk < 324 * 8; chunk += 256) {
      int s = chunk >> 3;
      int c8 = chunk & 7;
      int iy = s / 18;
      int ix = s - iy * 18;
      int hs = h0 + iy, wsp = w0 + ix;
      float4 f0 = make_float4(0.f, 0.f, 0.f, 0.f), f1 = make_float4(0.f, 0.f, 0.f, 0.f);
      if (hs < H_ && wsp < W_) {
        const float* p = xb + (size_t)(hs * W_ + wsp) * C_ + half * 64 + c8 * 8;
        f0 = *(const float4*)p;
        f1 = *(const float4*)(p + 4);
      }
      bf16x8 v;
      v[0] = (__bf16)f0.x; v[1] = (__bf16)f0.y; v[2] = (__bf16)f0.z; v[3] = (__bf16)f0.w;
      v[4] = (__bf16)f1.x; v[5] = (__bf16)f1.y; v[6] = (__bf16)f1.z; v[7] = (__bf16)f1.w;
      int lin = s * 128 + c8 * 16;
      *(bf16x8*)(&ldsA[lin ^ ((s & 7) << 4)]) = v;
    }
    // 18 K-steps of 32 channels: tap 0..8 x half-channel-chunk 0..1
    for (int ks = 0; ks < 18; ++ks) {
      __syncthreads();                 // prior step's ldsB reads done / ldsA staged
      ((uint4*)ldsB)[tid] = t0;
      ((uint4*)ldsB)[256 + tid] = t1;
      int u = half * 18 + ks + 1;      // next linear step
      if (u < 36) {
        int h2 = u / 18, k2 = u - (u / 18) * 18;
        int tile = (k2 >> 1) * 4 + h2 * 2 + (k2 & 1);
        t0 = wp4[tile * 512 + tid];
        t1 = wp4[tile * 512 + 256 + tid];
      }
      __syncthreads();                 // ldsB visible

      int tap = ks >> 1, kch = ks & 1;
      int dyv = tap / 3, dxv = tap - dyv * 3;

      bf16x8 a[4];
#pragma unroll
      for (int mi = 0; mi < 4; ++mi) {
        int srow = (wid * 4 + mi + dyv) * 18 + dxv + (lane & 15);
        int lin = srow * 128 + kch * 64 + koff;
        a[mi] = *(const bf16x8*)(&ldsA[lin ^ ((srow & 7) << 4)]);
      }
      bf16x8 bfr[8];
#pragma unroll
      for (int nb = 0; nb < 8; ++nb)
        bfr[nb] = *(const bf16x8*)(&ldsB[krow + nb * 256 + colb]);
#pragma unroll
      for (int mi = 0; mi < 4; ++mi)
#pragma unroll
        for (int nb = 0; nb < 8; ++nb)
          acc[mi][nb] = __builtin_amdgcn_mfma_f32_16x16x32_bf16(a[mi], bfr[nb], acc[mi][nb], 0, 0, 0);
    }
  }

  // epilogue: BN + ReLU + scatter. D frag: col=lane&15, row=(lane>>4)*4+reg
  const int colc = lane & 15;
  float* yb = y + (((size_t)bn * H_ + h0) * W_ + w0) * C_;
#pragma unroll
  for (int mi = 0; mi < 4; ++mi) {
    int oy = wid * 4 + mi;
#pragma unroll
    for (int r = 0; r < 4; ++r) {
      int ox = (lane >> 4) * 4 + r;
      float* yr = yb + ((size_t)oy * W_ + ox) * C_;
#pragma unroll
      for (int nb = 0; nb < 8; ++nb) {
        float v = acc[mi][nb][r] * sc[nb] + sh[nb];
        yr[nb * 16 + colc] = fmaxf(v, 0.f);
      }
    }
  }
}

extern "C" void kernel_launch(void* const* d_in, const int* in_sizes, int n_in,
                              void* d_out, int out_size, void* d_ws, size_t ws_size,
                              hipStream_t stream) {
  const float* x     = (const float*)d_in[0];
  const float* w     = (const float*)d_in[1];
  const float* b     = (const float*)d_in[2];
  const float* gamma = (const float*)d_in[3];
  const float* beta  = (const float*)d_in[4];
  const float* mean  = (const float*)d_in[5];
  const float* var   = (const float*)d_in[6];
  const int*   act   = (const int*)d_in[7];
  float* y = (float*)d_out;
  char* ws = (char*)d_ws;
  __bf16* wprep = (__bf16*)ws;
  float* scale = (float*)(ws + SCALE_OFF);
  float* shift = (float*)(ws + SHIFT_OFF);
  int* flags = (int*)(ws + FLAGS_OFF);

  prep_w_kernel<<<dim3(576), dim3(256), 0, stream>>>(w, wprep);
  prep_misc_kernel<<<dim3(4), dim3(256), 0, stream>>>(b, gamma, beta, mean, var, scale, shift, flags);
  flags_set_kernel<<<dim3(2), dim3(256), 0, stream>>>(act, flags);
  copy_kernel<<<dim3(NBPOS), dim3(256), 0, stream>>>(x, flags, y);
  conv_kernel<<<dim3(NACT), dim3(256), 0, stream>>>(x, wprep, scale, shift, act, y);
}

// Round 2
// 81.208 us; speedup vs baseline: 1.0130x; 1.0130x over previous
//
#include <hip/hip_runtime.h>
#include <hip/hip_bf16.h>

#define H_ 256
#define W_ 256
#define C_ 128
#define NBPOS 1024   // N * 16 * 16 block positions
#define NACT 512

typedef __bf16 bf16x8 __attribute__((ext_vector_type(8)));
typedef float f32x4 __attribute__((ext_vector_type(4)));

// workspace layout (bytes)
#define SCALE_OFF 294912
#define SHIFT_OFF 295424
#define FLAGS_OFF 295936

// Repack weights HWIO fp32 -> bf16 tiles [tap][cin8][cout][8] (tile = tap*4+kc, 4096 bf16 each)
__global__ void prep_w_kernel(const float* __restrict__ w, __bf16* __restrict__ wprep) {
  int o = blockIdx.x * 256 + threadIdx.x;      // 576*256 = 147456 exact
  int j = o & 7;
  int cout = (o >> 3) & 127;
  int k8 = (o >> 10) & 15;
  int tap = o >> 14;
  int cin = k8 * 8 + j;
  wprep[o] = (__bf16)w[((size_t)tap * 128 + cin) * 128 + cout];
}

// BN fold + flag clear
__global__ void prep_misc_kernel(const float* __restrict__ b, const float* __restrict__ gamma,
                                 const float* __restrict__ beta, const float* __restrict__ mean,
                                 const float* __restrict__ var,
                                 float* __restrict__ scale, float* __restrict__ shift,
                                 int* __restrict__ flags) {
  int i = blockIdx.x * 256 + threadIdx.x;      // grid 4 -> 1024 threads
  if (i < 128) {
    float s = gamma[i] / sqrtf(var[i] + 1e-3f);
    scale[i] = s;
    shift[i] = (b[i] - mean[i]) * s + beta[i];
  }
  if (i < NBPOS) flags[i] = 0;
}

__global__ void flags_set_kernel(const int* __restrict__ active, int* __restrict__ flags) {
  int i = blockIdx.x * 256 + threadIdx.x;
  if (i < NACT) flags[active[i]] = 1;
}

// Copy non-active 16x16 blocks x -> y (active blocks written by conv kernel)
__global__ __launch_bounds__(256) void copy_kernel(const float* __restrict__ x,
                                                   const int* __restrict__ flags,
                                                   float* __restrict__ y) {
  int pb = blockIdx.x;
  if (flags[pb]) return;
  int bn = pb >> 8, by = (pb >> 4) & 15, bx = pb & 15;
  size_t base = (((size_t)bn * H_ + by * 16) * W_ + bx * 16) * C_;  // float index
  const float4* xs = (const float4*)x;
  float4* ys = (float4*)y;
  for (int i = threadIdx.x; i < 8192; i += 256) {   // 16 rows * 512 float4
    int row = i >> 9;
    int rem = i & 511;
    size_t idx4 = (base + (size_t)row * (W_ * C_)) / 4 + rem;
    ys[idx4] = xs[idx4];
  }
}

// One workgroup (4 waves, 256 thr) per active block.
// Implicit GEMM M=256 (16x16 spatial), N=128 (cout), K=1152 (9 taps * 128 cin).
// Patch staged bf16 in LDS in two 64-channel halves, XOR-swizzled.
__global__ __launch_bounds__(256, 2) void conv_kernel(
    const float* __restrict__ x, const __bf16* __restrict__ wprep,
    const float* __restrict__ scale, const float* __restrict__ shift,
    const int* __restrict__ active, float* __restrict__ y) {
  __shared__ unsigned char ldsA[324 * 128];   // 18*18 spatial x 64ch bf16 = 41472 B (swizzled)
  __shared__ unsigned char ldsB[8192];        // 32k x 128cout bf16 weight tile

  const int tid = threadIdx.x;
  const int lane = tid & 63;
  const int wid = tid >> 6;
  const int aid = active[blockIdx.x];
  const int bn = aid >> 8;
  const int by = (aid >> 4) & 15;
  const int bx = aid & 15;
  const int h0 = by * 16, w0 = bx * 16;
  const float* xb = x + (size_t)bn * (H_ * W_ * C_);

  // per-lane BN constants for epilogue (cout = nb*16 + (lane&15))
  float sc[8], sh[8];
  {
    int col = lane & 15;
#pragma unroll
    for (int nb = 0; nb < 8; ++nb) {
      sc[nb] = scale[nb * 16 + col];
      sh[nb] = shift[nb * 16 + col];
    }
  }

  f32x4 acc[4][8];
  f32x4 zero = {0.f, 0.f, 0.f, 0.f};
#pragma unroll
  for (int i = 0; i < 4; ++i)
#pragma unroll
    for (int j = 0; j < 8; ++j) acc[i][j] = zero;

  const uint4* wp4 = (const uint4*)wprep;
  // prefetch weight tile for u=0 (tap0, kc0)
  uint4 t0 = wp4[tid];
  uint4 t1 = wp4[256 + tid];

  const int koff = (lane >> 4) * 16;        // 16B k-chunk within 32 channels
  const int colb = (lane & 15) * 16;
  const int krow = (lane >> 4) * 2048;

  for (int half = 0; half < 2; ++half) {
    __syncthreads();  // all waves done reading ldsA from previous half
    // stage 18x18 x 64ch patch as bf16, swizzled: byte ^= (spatial&7)<<4
    for (int chunk = tid; chunk < 324 * 8; chunk += 256) {
      int s = chunk >> 3;
      int c8 = chunk & 7;
      int iy = s / 18;
      int ix = s - iy * 18;
      int hs = h0 + iy, wsp = w0 + ix;
      float4 f0 = make_float4(0.f, 0.f, 0.f, 0.f), f1 = make_float4(0.f, 0.f, 0.f, 0.f);
      if (hs < H_ && wsp < W_) {
        const float* p = xb + (size_t)(hs * W_ + wsp) * C_ + half * 64 + c8 * 8;
        f0 = *(const float4*)p;
        f1 = *(const float4*)(p + 4);
      }
      bf16x8 v;
      v[0] = (__bf16)f0.x; v[1] = (__bf16)f0.y; v[2] = (__bf16)f0.z; v[3] = (__bf16)f0.w;
      v[4] = (__bf16)f1.x; v[5] = (__bf16)f1.y; v[6] = (__bf16)f1.z; v[7] = (__bf16)f1.w;
      int lin = s * 128 + c8 * 16;
      *(bf16x8*)(&ldsA[lin ^ ((s & 7) << 4)]) = v;
    }
    // 18 K-steps of 32 channels: tap 0..8 x half-channel-chunk 0..1
    for (int ks = 0; ks < 18; ++ks) {
      __syncthreads();                 // prior step's ldsB reads done / ldsA staged
      ((uint4*)ldsB)[tid] = t0;
      ((uint4*)ldsB)[256 + tid] = t1;
      int u = half * 18 + ks + 1;      // next linear step
      if (u < 36) {
        int h2 = u / 18, k2 = u - (u / 18) * 18;
        int tile = (k2 >> 1) * 4 + h2 * 2 + (k2 & 1);
        t0 = wp4[tile * 512 + tid];
        t1 = wp4[tile * 512 + 256 + tid];
      }
      __syncthreads();                 // ldsB visible

      int tap = ks >> 1, kch = ks & 1;
      int dyv = tap / 3, dxv = tap - dyv * 3;

      bf16x8 a[4];
#pragma unroll
      for (int mi = 0; mi < 4; ++mi) {
        int srow = (wid * 4 + mi + dyv) * 18 + dxv + (lane & 15);
        int lin = srow * 128 + kch * 64 + koff;
        a[mi] = *(const bf16x8*)(&ldsA[lin ^ ((srow & 7) << 4)]);
      }
      bf16x8 bfr[8];
#pragma unroll
      for (int nb = 0; nb < 8; ++nb)
        bfr[nb] = *(const bf16x8*)(&ldsB[krow + nb * 256 + colb]);
#pragma unroll
      for (int mi = 0; mi < 4; ++mi)
#pragma unroll
        for (int nb = 0; nb < 8; ++nb)
          acc[mi][nb] = __builtin_amdgcn_mfma_f32_16x16x32_bf16(a[mi], bfr[nb], acc[mi][nb], 0, 0, 0);
    }
  }

  // epilogue: BN + ReLU + scatter. D frag: col=lane&15, row=(lane>>4)*4+reg
  const int colc = lane & 15;
  float* yb = y + (((size_t)bn * H_ + h0) * W_ + w0) * C_;
#pragma unroll
  for (int mi = 0; mi < 4; ++mi) {
    int oy = wid * 4 + mi;
#pragma unroll
    for (int r = 0; r < 4; ++r) {
      int ox = (lane >> 4) * 4 + r;
      float* yr = yb + ((size_t)oy * W_ + ox) * C_;
#pragma unroll
      for (int nb = 0; nb < 8; ++nb) {
        float v = acc[mi][nb][r] * sc[nb] + sh[nb];
        yr[nb * 16 + colc] = fmaxf(v, 0.f);
      }
    }
  }
}

extern "C" void kernel_launch(void* const* d_in, const int* in_sizes, int n_in,
                              void* d_out, int out_size, void* d_ws, size_t ws_size,
                              hipStream_t stream) {
  const float* x     = (const float*)d_in[0];
  const float* w     = (const float*)d_in[1];
  const float* b     = (const float*)d_in[2];
  const float* gamma = (const float*)d_in[3];
  const float* beta  = (const float*)d_in[4];
  const float* mean  = (const float*)d_in[5];
  const float* var   = (const float*)d_in[6];
  const int*   act   = (const int*)d_in[7];
  float* y = (float*)d_out;
  char* ws = (char*)d_ws;
  __bf16* wprep = (__bf16*)ws;
  float* scale = (float*)(ws + SCALE_OFF);
  float* shift = (float*)(ws + SHIFT_OFF);
  int* flags = (int*)(ws + FLAGS_OFF);

  prep_w_kernel<<<dim3(576), dim3(256), 0, stream>>>(w, wprep);
  prep_misc_kernel<<<dim3(4), dim3(256), 0, stream>>>(b, gamma, beta, mean, var, scale, shift, flags);
  flags_set_kernel<<<dim3(2), dim3(256), 0, stream>>>(act, flags);
  copy_kernel<<<dim3(NBPOS), dim3(256), 0, stream>>>(x, flags, y);
  conv_kernel<<<dim3(NACT), dim3(256), 0, stream>>>(x, wprep, scale, shift, act, y);
}